// Round 2
// baseline (483.728 us; speedup 1.0000x reference)
//
#include <hip/hip_runtime.h>
#include <hip/hip_cooperative_groups.h>
#include <math.h>

namespace cg = cooperative_groups;

#define NN 96
#define DD 512
#define PP 9120          // NN*(NN-1)
#define EPSF 1e-8f
#define INV_TEMP 100.0f
#define LOG2E 1.4426950408889634f
#define RT 8             // tasks (rows/cols of mma) per lse task-block
#define NTASK (2*PP)     // 18240
#define NBLK_T (NTASK/RT) // 2280 lse task-blocks
#define CBASE (PP/RT)    // 1140: first task-block index handling column tasks
#define GRID 512         // cooperative grid: 2 blocks/CU — large occupancy margin
#define GSZ (NN*NN)      // 9216

// ws float-offset layout
#define OFF_PART  0        // 12 partial grams [zz][9216] (fused) / 6 (classic)
#define OFF_G     110592   // G  = txt*img^T   [96*96]
#define OFF_GT    119808   // GT = G^T
#define OFF_WT    129024   // wt[k][l] = 1/(||t_k-t_l||+eps), diag 0
#define OFF_WM    138240
#define OFF_WST   147456   // wt * log2e
#define OFF_WSM   156672   // wm * log2e
#define OFF_DIAG  165888   // diag[p]
#define OFF_WMAX  175008   // [0]=max wt, [1]=max wm (uint bits)
#define OFF_BSUM  175012   // per-block partial sums

__device__ __forceinline__ void decomp(unsigned p, int& i, int& j) {
    unsigned ii = p / 95u;
    unsigned r  = p - ii * 95u;
    i = (int)ii;
    j = (int)(r + (r >= ii ? 1u : 0u));
}

// ======================= fused cooperative kernel =======================
__global__ __launch_bounds__(256, 2) void fused_kernel(const float* __restrict__ txt,
                                                       const float* __restrict__ img,
                                                       float* __restrict__ ws,
                                                       float* __restrict__ out) {
    __shared__ float4 GA[16][33];
    __shared__ float4 GB[16][33];
    __shared__ float A[RT * NN];
    __shared__ float M2s[RT];
    __shared__ float Ms[RT];
    __shared__ float wred[4][RT];
    __shared__ float credS[RT];
    __shared__ float red[256];

    cg::grid_group gg = cg::this_grid();
    int b = blockIdx.x, tid = threadIdx.x;

    // phase 0: init WMAX (consumed after first grid sync)
    if (b == 0 && tid < 2) ((unsigned int*)(ws + OFF_WMAX))[tid] = 0u;

    // ---------- phase 1: split-K gram partials, 432 tasks ----------
    if (b < 432) {
        int zz = b / 36;
        int tile = b - zz * 36;
        int z = zz >> 2, ks = zz & 3;
        int a0 = (tile / 6) * 16, b0 = (tile % 6) * 16;
        const float* X = (z == 2) ? img : txt;
        const float* Y = (z == 0) ? img : ((z == 1) ? txt : img);
        const float4* Xp = (const float4*)X;     // row stride 128 float4
        const float4* Yp = (const float4*)Y;
        int r = tid >> 5, c = tid & 31;
        int kbase = ks * 32;
        #pragma unroll
        for (int rep = 0; rep < 2; ++rep) {
            int row = rep * 8 + r;
            GA[row][c] = Xp[(a0 + row) * 128 + kbase + c];
            GB[row][c] = Yp[(b0 + row) * 128 + kbase + c];
        }
        __syncthreads();
        int al = tid >> 4, bl = tid & 15;
        float acc = 0.f;
        #pragma unroll 8
        for (int kk = 0; kk < 32; ++kk) {
            float4 av = GA[al][kk];
            float4 bv = GB[bl][kk];
            acc += av.x*bv.x + av.y*bv.y + av.z*bv.z + av.w*bv.w;
        }
        ws[OFF_PART + zz * GSZ + (a0 + al) * NN + (b0 + bl)] = acc;
    }
    __threadfence();
    gg.sync();
    __threadfence();

    // ---------- phase 2: pairs (first 36 blocks carry the 9216 items) ----------
    {
        int t = b * 256 + tid;
        if (t < GSZ) {
            int k = t / NN, l = t - k * NN;
            const float* P = ws + OFF_PART;
            #define RD(z, x) (P[(4*(z))*GSZ + (x)] + P[(4*(z)+1)*GSZ + (x)] + \
                              P[(4*(z)+2)*GSZ + (x)] + P[(4*(z)+3)*GSZ + (x)])
            float gkl = RD(0, k*NN + l);
            float glk = RD(0, l*NN + k);
            ws[OFF_G  + t] = gkl;
            ws[OFF_GT + t] = glk;
            float wtv = 0.f, wmv = 0.f;
            if (k != l) {
                float nt2 = RD(1, k*NN+k) - 2.f*RD(1, k*NN+l) + RD(1, l*NN+l);
                float nm2 = RD(2, k*NN+k) - 2.f*RD(2, k*NN+l) + RD(2, l*NN+l);
                wtv = 1.f / (sqrtf(fmaxf(nt2, 0.f)) + EPSF);
                wmv = 1.f / (sqrtf(fmaxf(nm2, 0.f)) + EPSF);
                atomicMax((unsigned int*)(ws + OFF_WMAX) + 0, __float_as_uint(wtv));
                atomicMax((unsigned int*)(ws + OFF_WMAX) + 1, __float_as_uint(wmv));
                int p = k * 95 + l - (l > k ? 1 : 0);
                float gkk = RD(0, k*NN+k), gll = RD(0, l*NN+l);
                ws[OFF_DIAG + p] = INV_TEMP * wtv * wmv * (gkk - gkl - glk + gll);
            }
            #undef RD
            ws[OFF_WT  + t] = wtv;
            ws[OFF_WM  + t] = wmv;
            ws[OFF_WST + t] = wtv * LOG2E;
            ws[OFF_WSM + t] = wmv * LOG2E;
        }
    }
    __threadfence();
    gg.sync();
    __threadfence();

    // ---------- phase 3: lse, grid-stride over 2280 task-blocks ----------
    int lane = tid & 63, wv = tid >> 6;
    float csum = 0.f;                 // meaningful on tid<RT
    for (int tb = b; tb < NBLK_T; tb += GRID) {
        bool is_col = (tb >= CBASE);
        const float* Mat    = ws + (is_col ? OFF_GT  : OFF_G);
        const float* wself  = ws + (is_col ? OFF_WM  : OFF_WT);
        const float* wsweep = ws + (is_col ? OFF_WST : OFF_WSM);
        float Wmax = __uint_as_float(((const unsigned int*)(ws + OFF_WMAX))[is_col ? 0 : 1]);
        int base = (tb - (is_col ? CBASE : 0)) * RT;

        #pragma unroll
        for (int q = 0; q < 2; ++q) {
            int rr = 2 * wv + q;
            int i, j; decomp((unsigned)(base + rr), i, j);
            float s = INV_TEMP * wself[i * NN + j];
            const float* Mi = Mat + i * NN;
            const float* Mj = Mat + j * NN;
            float v0 = s * (Mi[lane] - Mj[lane]);
            A[rr * NN + lane] = v0;
            float vmax = v0, vmin = v0;
            if (lane < 32) {
                float v1 = s * (Mi[64 + lane] - Mj[64 + lane]);
                A[rr * NN + 64 + lane] = v1;
                vmax = fmaxf(vmax, v1); vmin = fminf(vmin, v1);
            }
            #pragma unroll
            for (int off = 32; off > 0; off >>= 1) {
                vmax = fmaxf(vmax, __shfl_xor(vmax, off, 64));
                vmin = fminf(vmin, __shfl_xor(vmin, off, 64));
            }
            if (lane == 0) {
                float M = Wmax * (vmax - vmin);
                Ms[rr] = M;
                M2s[rr] = M * LOG2E;
            }
        }
        __syncthreads();

        int l1 = (lane < 32) ? (64 + lane) : (lane - 32);
        float M2[RT], aL0[RT], aL1[RT], aL2[RT], S[RT];
        #pragma unroll
        for (int r = 0; r < RT; ++r) {
            M2[r] = M2s[r];
            aL0[r] = A[r * NN + lane];
            aL1[r] = A[r * NN + l1];
            aL2[r] = A[r * NN + lane + 32];
            S[r] = 0.f;
        }

        for (int idx = wv; idx < 48; idx += 4) {
            int k0 = 2 * idx, k1 = k0 + 1;
            float w0 = wsweep[k0 * NN + lane];
            float w1 = wsweep[(lane < 32 ? k0 : k1) * NN + l1];
            float w2 = wsweep[k1 * NN + lane + 32];
            #pragma unroll
            for (int r = 0; r < RT; ++r) {
                float2 ak = *(const float2*)&A[r * NN + k0];   // k0 even -> 8B aligned
                float aksel = (lane < 32) ? ak.x : ak.y;
                S[r] += __builtin_amdgcn_exp2f(w0 * (ak.x  - aL0[r]) - M2[r])
                      + __builtin_amdgcn_exp2f(w1 * (aksel - aL1[r]) - M2[r])
                      + __builtin_amdgcn_exp2f(w2 * (ak.y  - aL2[r]) - M2[r]);
            }
        }

        #pragma unroll
        for (int off = 32; off > 0; off >>= 1) {
            #pragma unroll
            for (int r = 0; r < RT; ++r) S[r] += __shfl_xor(S[r], off, 64);
        }
        if (lane == 0) {
            #pragma unroll
            for (int r = 0; r < RT; ++r) wred[wv][r] = S[r];
        }
        __syncthreads();

        if (tid < RT) {
            float tot = wred[0][tid] + wred[1][tid] + wred[2][tid] + wred[3][tid];
            tot -= 96.f * __builtin_amdgcn_exp2f(-M2s[tid]);   // remove w=0 diagonal slots
            csum += Ms[tid] + logf(tot) - ws[OFF_DIAG + base + tid];
        }
        __syncthreads();   // protect A/M2s/wred before next task's build
    }

    if (tid < RT) credS[tid] = csum;
    __syncthreads();
    if (tid == 0) {
        float cpart = 0.f;
        #pragma unroll
        for (int r = 0; r < RT; ++r) cpart += credS[r];
        ws[OFF_BSUM + b] = cpart;
    }
    __threadfence();
    gg.sync();
    __threadfence();

    // ---------- phase 4: final reduce (block 0) ----------
    if (b == 0) {
        float s = 0.f;
        for (int i = tid; i < GRID; i += 256)
            s += ws[OFF_BSUM + i];
        red[tid] = s; __syncthreads();
        for (int t = 128; t > 0; t >>= 1) {
            if (tid < t) red[tid] += red[tid + t];
            __syncthreads();
        }
        if (tid == 0) out[0] = red[0] * (1.0f / (float)NTASK);
    }
}

// ======================= classic fallback path (round-0, proven) =======================
__global__ __launch_bounds__(256) void gram_kernel(const float* __restrict__ txt,
                                                   const float* __restrict__ img,
                                                   float* __restrict__ ws) {
    __shared__ float4 Al[16][65];
    __shared__ float4 Bl[16][65];
    if (blockIdx.x == 0 && blockIdx.y == 0 && blockIdx.z == 0 && threadIdx.x < 2)
        ((unsigned int*)(ws + OFF_WMAX))[threadIdx.x] = 0u;   // replaces host memset
    int zz = blockIdx.z;
    int z = zz >> 1, ks = zz & 1;
    int a0 = blockIdx.x * 16, b0 = blockIdx.y * 16;
    const float* X = (z == 2) ? img : txt;
    const float* Y = (z == 0) ? img : ((z == 1) ? txt : img);
    const float4* Xp = (const float4*)X;
    const float4* Yp = (const float4*)Y;
    int tid = threadIdx.x;
    int r = tid >> 6, c = tid & 63;
    int kbase = ks * 64;
    #pragma unroll
    for (int rep = 0; rep < 4; ++rep) {
        int row = rep * 4 + r;
        Al[row][c] = Xp[(a0 + row) * 128 + kbase + c];
        Bl[row][c] = Yp[(b0 + row) * 128 + kbase + c];
    }
    __syncthreads();
    int al = tid >> 4, bl = tid & 15;
    float acc = 0.f;
    #pragma unroll 8
    for (int kk = 0; kk < 64; ++kk) {
        float4 av = Al[al][kk];
        float4 bv = Bl[bl][kk];
        acc += av.x*bv.x + av.y*bv.y + av.z*bv.z + av.w*bv.w;
    }
    ws[OFF_PART + zz * GSZ + (a0 + al) * NN + (b0 + bl)] = acc;
}

__global__ void pairs_kernel(float* __restrict__ ws) {
    int t = blockIdx.x * 256 + threadIdx.x;
    if (t >= GSZ) return;
    int k = t / NN, l = t - k * NN;
    const float* P = ws + OFF_PART;
    #define RD2(z, x) (P[(2*(z)) * GSZ + (x)] + P[(2*(z)+1) * GSZ + (x)])
    float gkl = RD2(0, k*NN + l);
    float glk = RD2(0, l*NN + k);
    ws[OFF_G  + t] = gkl;
    ws[OFF_GT + t] = glk;
    float wtv = 0.f, wmv = 0.f;
    if (k != l) {
        float nt2 = RD2(1, k*NN+k) - 2.f*RD2(1, k*NN+l) + RD2(1, l*NN+l);
        float nm2 = RD2(2, k*NN+k) - 2.f*RD2(2, k*NN+l) + RD2(2, l*NN+l);
        wtv = 1.f / (sqrtf(fmaxf(nt2, 0.f)) + EPSF);
        wmv = 1.f / (sqrtf(fmaxf(nm2, 0.f)) + EPSF);
        atomicMax((unsigned int*)(ws + OFF_WMAX) + 0, __float_as_uint(wtv));
        atomicMax((unsigned int*)(ws + OFF_WMAX) + 1, __float_as_uint(wmv));
        int p = k * 95 + l - (l > k ? 1 : 0);
        float gkk = RD2(0, k*NN+k), gll = RD2(0, l*NN+l);
        ws[OFF_DIAG + p] = INV_TEMP * wtv * wmv * (gkk - gkl - glk + gll);
    }
    #undef RD2
    ws[OFF_WT  + t] = wtv;
    ws[OFF_WM  + t] = wmv;
    ws[OFF_WST + t] = wtv * LOG2E;
    ws[OFF_WSM + t] = wmv * LOG2E;
}

__global__ __launch_bounds__(256) void lse_kernel(float* __restrict__ ws) {
    __shared__ float A[RT * NN];
    __shared__ float M2s[RT];
    __shared__ float Ms[RT];
    __shared__ float wred[4][RT];
    __shared__ float cred[RT];

    int tid = threadIdx.x, lane = tid & 63, wv = tid >> 6;
    int b = blockIdx.x;
    bool is_col = (b >= CBASE);
    const float* Mat    = ws + (is_col ? OFF_GT  : OFF_G);
    const float* wself  = ws + (is_col ? OFF_WM  : OFF_WT);
    const float* wsweep = ws + (is_col ? OFF_WST : OFF_WSM);
    float Wmax = __uint_as_float(((const unsigned int*)(ws + OFF_WMAX))[is_col ? 0 : 1]);
    int base = (b - (is_col ? CBASE : 0)) * RT;

    #pragma unroll
    for (int q = 0; q < 2; ++q) {
        int rr = 2 * wv + q;
        int i, j; decomp((unsigned)(base + rr), i, j);
        float s = INV_TEMP * wself[i * NN + j];
        const float* Mi = Mat + i * NN;
        const float* Mj = Mat + j * NN;
        float v0 = s * (Mi[lane] - Mj[lane]);
        A[rr * NN + lane] = v0;
        float vmax = v0, vmin = v0;
        if (lane < 32) {
            float v1 = s * (Mi[64 + lane] - Mj[64 + lane]);
            A[rr * NN + 64 + lane] = v1;
            vmax = fmaxf(vmax, v1); vmin = fminf(vmin, v1);
        }
        #pragma unroll
        for (int off = 32; off > 0; off >>= 1) {
            vmax = fmaxf(vmax, __shfl_xor(vmax, off, 64));
            vmin = fminf(vmin, __shfl_xor(vmin, off, 64));
        }
        if (lane == 0) {
            float M = Wmax * (vmax - vmin);
            Ms[rr] = M;
            M2s[rr] = M * LOG2E;
        }
    }
    __syncthreads();

    int l1 = (lane < 32) ? (64 + lane) : (lane - 32);
    float M2[RT], aL0[RT], aL1[RT], aL2[RT], S[RT];
    #pragma unroll
    for (int r = 0; r < RT; ++r) {
        M2[r] = M2s[r];
        aL0[r] = A[r * NN + lane];
        aL1[r] = A[r * NN + l1];
        aL2[r] = A[r * NN + lane + 32];
        S[r] = 0.f;
    }

    for (int idx = wv; idx < 48; idx += 4) {
        int k0 = 2 * idx, k1 = k0 + 1;
        float w0 = wsweep[k0 * NN + lane];
        float w1 = wsweep[(lane < 32 ? k0 : k1) * NN + l1];
        float w2 = wsweep[k1 * NN + lane + 32];
        #pragma unroll
        for (int r = 0; r < RT; ++r) {
            float2 ak = *(const float2*)&A[r * NN + k0];
            float aksel = (lane < 32) ? ak.x : ak.y;
            S[r] += __builtin_amdgcn_exp2f(w0 * (ak.x  - aL0[r]) - M2[r])
                  + __builtin_amdgcn_exp2f(w1 * (aksel - aL1[r]) - M2[r])
                  + __builtin_amdgcn_exp2f(w2 * (ak.y  - aL2[r]) - M2[r]);
        }
    }

    #pragma unroll
    for (int off = 32; off > 0; off >>= 1) {
        #pragma unroll
        for (int r = 0; r < RT; ++r) S[r] += __shfl_xor(S[r], off, 64);
    }
    if (lane == 0) {
        #pragma unroll
        for (int r = 0; r < RT; ++r) wred[wv][r] = S[r];
    }
    __syncthreads();

    if (tid < RT) {
        int r = tid;
        float tot = wred[0][r] + wred[1][r] + wred[2][r] + wred[3][r];
        tot -= 96.f * __builtin_amdgcn_exp2f(-M2s[r]);
        cred[r] = Ms[r] + logf(tot) - ws[OFF_DIAG + base + r];
    }
    __syncthreads();
    if (tid == 0) {
        float c = 0.f;
        #pragma unroll
        for (int r = 0; r < RT; ++r) c += cred[r];
        ws[OFF_BSUM + b] = c;
    }
}

__global__ void final_kernel(const float* __restrict__ ws, float* __restrict__ out) {
    __shared__ float red[256];
    int tid = threadIdx.x;
    float s = 0.f;
    for (int i = tid; i < (NTASK/RT); i += 256)
        s += ws[OFF_BSUM + i];
    red[tid] = s; __syncthreads();
    for (int t = 128; t > 0; t >>= 1) {
        if (tid < t) red[tid] += red[tid + t];
        __syncthreads();
    }
    if (tid == 0) out[0] = red[0] * (1.0f / (float)NTASK);
}

static void launch_classic(const float* txt, const float* img, float* ws, float* out,
                           hipStream_t stream) {
    gram_kernel<<<dim3(6, 6, 6), 256, 0, stream>>>(txt, img, ws);
    pairs_kernel<<<36, 256, 0, stream>>>(ws);
    lse_kernel<<<NTASK/RT, 256, 0, stream>>>(ws);
    final_kernel<<<1, 256, 0, stream>>>(ws, out);
}

extern "C" void kernel_launch(void* const* d_in, const int* in_sizes, int n_in,
                              void* d_out, int out_size, void* d_ws, size_t ws_size,
                              hipStream_t stream) {
    const float* txt = (const float*)d_in[0];
    const float* img = (const float*)d_in[1];
    float* ws = (float*)d_ws;
    float* out = (float*)d_out;

    static int mode = -1;   // 1 = cooperative fused, 0 = classic
    if (mode < 0) {
        int dev = 0;
        (void)hipGetDevice(&dev);
        int numCU = 0;
        if (hipDeviceGetAttribute(&numCU, hipDeviceAttributeMultiprocessorCount, dev)
                != hipSuccess || numCU <= 0)
            numCU = 256;
        int maxB = 0;
        hipError_t e = hipOccupancyMaxActiveBlocksPerMultiprocessor(
            &maxB, (const void*)fused_kernel, 256, 0);
        mode = (e == hipSuccess && maxB * numCU >= GRID) ? 1 : 0;
    }

    if (mode == 1) {
        void* args[4] = { (void*)&txt, (void*)&img, (void*)&ws, (void*)&out };
        hipError_t e = hipLaunchCooperativeKernel((const void*)fused_kernel,
                                                  dim3(GRID), dim3(256), args, 0, stream);
        if (e == hipSuccess) return;
        mode = 0;   // runtime refused: fall back permanently
    }
    launch_classic(txt, img, ws, out, stream);
}

// Round 3
// 120.670 us; speedup vs baseline: 4.0087x; 4.0087x over previous
//
#include <hip/hip_runtime.h>
#include <math.h>

#define NN 96
#define DD 512
#define PP 9120          // NN*(NN-1)
#define EPSF 1e-8f
#define INV_TEMP 100.0f
#define LOG2E 1.4426950408889634f
#define RT 8             // tasks (rows/cols of mma) per lse block
#define NTASK (2*PP)     // 18240
#define NBLK_T (NTASK/RT) // 2280
#define CBASE (PP/RT)    // 1140: first block index handling column tasks
#define GSZ (NN*NN)      // 9216

// ws float-offset layout (no init-dependent state anywhere: poison-proof)
#define OFF_G     110592   // G  = txt*img^T   [96*96]
#define OFF_GT    119808   // GT = G^T
#define OFF_WT    129024   // wt[k][l] = 1/(||t_k-t_l||+eps), diag 0
#define OFF_WM    138240
#define OFF_WST   147456   // wt * log2e
#define OFF_WSM   156672   // wm * log2e
#define OFF_DIAG  165888   // diag[p]
#define OFF_WMAXS 175008   // [0..35] per-tile max wt, [36..71] per-tile max wm

__device__ __forceinline__ void decomp(unsigned p, int& i, int& j) {
    unsigned ii = p / 95u;
    unsigned r  = p - ii * 95u;
    i = (int)ii;
    j = (int)(r + (r >= ii ? 1u : 0u));
}

// K1: 36 blocks; block (a,b) owns the 16x16 pair-tile (rows i in a-group, j in b-group).
// Loads t[a],t[b],m[a],m[b] row-groups in 4 K-chunks; computes G/GT tiles, direct-diff
// norms, W tables, diag, per-tile maxima. No cross-block deps, no atomics.
__global__ __launch_bounds__(256) void prep_kernel(const float* __restrict__ txt,
                                                   const float* __restrict__ img,
                                                   float* __restrict__ ws) {
    __shared__ float4 tA[16][33], tB[16][33], mA[16][33], mB[16][33];
    __shared__ float gdia[32];    // <t_r,m_r> for r in a-group [0..15], b-group [16..31]
    __shared__ float wmaxs[8];

    int b = blockIdx.x, tid = threadIdx.x;
    int a = b / 6, bb = b - a * 6;
    int k = tid >> 4, l = tid & 15;
    int lane = tid & 63, wv = tid >> 6;
    const float4* T4 = (const float4*)txt;   // row stride 128 float4
    const float4* M4 = (const float4*)img;

    // loader mapping: 4 arrays x 16 rows x 32 f4 per stage; each thread 8 f4
    int warr = tid >> 6;          // 0:tA 1:tB 2:mA 3:mB
    int lrow = (tid >> 2) & 15;
    int lc0  = (tid & 3) * 8;
    const float4* lsrc = (warr >= 2) ? M4 : T4;
    int lgrow = ((warr & 1) ? bb : a) * 16 + lrow;
    float4* ldst = (warr == 0 ? &tA[0][0] : warr == 1 ? &tB[0][0] :
                    warr == 2 ? &mA[0][0] : &mB[0][0]) + lrow * 33 + lc0;
    const float4* gsrc = lsrc + lgrow * 128 + lc0;

    float gij = 0.f, gji = 0.f, nt2 = 0.f, nm2 = 0.f, gdacc = 0.f;

    for (int st = 0; st < 4; ++st) {
        if (st) __syncthreads();          // previous stage's reads done
        #pragma unroll
        for (int u = 0; u < 8; ++u)
            ldst[u] = gsrc[st * 32 + u];
        __syncthreads();
        #pragma unroll
        for (int q = 0; q < 32; ++q) {
            float4 ta = tA[k][q], tb = tB[l][q], ma = mA[k][q], mb = mB[l][q];
            gij += ta.x*mb.x + ta.y*mb.y + ta.z*mb.z + ta.w*mb.w;   // <t_i, m_j>
            gji += tb.x*ma.x + tb.y*ma.y + tb.z*ma.z + tb.w*ma.w;   // <t_j, m_i>
            float d0 = ta.x-tb.x, d1 = ta.y-tb.y, d2 = ta.z-tb.z, d3 = ta.w-tb.w;
            nt2 += d0*d0 + d1*d1 + d2*d2 + d3*d3;                   // ||t_i-t_j||^2
            float e0 = ma.x-mb.x, e1 = ma.y-mb.y, e2 = ma.z-mb.z, e3 = ma.w-mb.w;
            nm2 += e0*e0 + e1*e1 + e2*e2 + e3*e3;                   // ||m_i-m_j||^2
        }
        if (tid < 32) {                   // diag <t_r, m_r> streams
            int rr = tid & 15;
            const float4* x = (tid < 16) ? &tA[rr][0] : &tB[rr][0];
            const float4* y = (tid < 16) ? &mA[rr][0] : &mB[rr][0];
            #pragma unroll
            for (int q = 0; q < 32; ++q) {
                float4 xv = x[q], yv = y[q];
                gdacc += xv.x*yv.x + xv.y*yv.y + xv.z*yv.z + xv.w*yv.w;
            }
        }
    }
    if (tid < 32) gdia[tid] = gdacc;
    __syncthreads();

    int i = a * 16 + k, j = bb * 16 + l;
    int t = i * NN + j;
    ws[OFF_G + t] = gij;
    ws[OFF_GT + j * NN + i] = gij;        // GT tile (b,a); mirror block covers (a,b)
    float wt = 0.f, wm = 0.f;
    if (i != j) {
        wt = 1.f / (sqrtf(fmaxf(nt2, 0.f)) + EPSF);
        wm = 1.f / (sqrtf(fmaxf(nm2, 0.f)) + EPSF);
        int p = i * 95 + j - (j > i ? 1 : 0);
        float gii = gdia[k], gjj = gdia[16 + l];
        ws[OFF_DIAG + p] = INV_TEMP * wt * wm * (gii - gij - gji + gjj);
    }
    ws[OFF_WT  + t] = wt;
    ws[OFF_WM  + t] = wm;
    ws[OFF_WST + t] = wt * LOG2E;
    ws[OFF_WSM + t] = wm * LOG2E;

    // per-tile maxima (plain stores; lse reduces 36 slots per table)
    float mt = wt, mw = wm;
    #pragma unroll
    for (int off = 32; off > 0; off >>= 1) {
        mt = fmaxf(mt, __shfl_xor(mt, off, 64));
        mw = fmaxf(mw, __shfl_xor(mw, off, 64));
    }
    if (lane == 0) { wmaxs[wv] = mt; wmaxs[4 + wv] = mw; }
    __syncthreads();
    if (tid == 0) {
        ws[OFF_WMAXS + b]      = fmaxf(fmaxf(wmaxs[0], wmaxs[1]), fmaxf(wmaxs[2], wmaxs[3]));
        ws[OFF_WMAXS + 36 + b] = fmaxf(fmaxf(wmaxs[4], wmaxs[5]), fmaxf(wmaxs[6], wmaxs[7]));
    }
}

// K2: proven lse structure (2280 blocks, full occupancy); Wmax from 36 tile slots;
// per-block contribution folded into out via one float atomicAdd (out pre-zeroed).
__global__ __launch_bounds__(256) void lse_kernel(const float* __restrict__ ws,
                                                  float* __restrict__ out) {
    __shared__ float A[RT * NN];
    __shared__ float M2s[RT];     // M * log2e
    __shared__ float Ms[RT];      // M
    __shared__ float wred[4][RT];
    __shared__ float cred[RT];

    int tid = threadIdx.x, lane = tid & 63, wv = tid >> 6;
    int b = blockIdx.x;
    bool is_col = (b >= CBASE);
    const float* Mat    = ws + (is_col ? OFF_GT  : OFF_G);
    const float* wself  = ws + (is_col ? OFF_WM  : OFF_WT);
    const float* wsweep = ws + (is_col ? OFF_WST : OFF_WSM);
    // rows sweep over wm (bound = max wm, slots 36..71); cols over wt (slots 0..35)
    float wl = (lane < 36) ? ws[OFF_WMAXS + (is_col ? 0 : 36) + lane] : 0.f;
    #pragma unroll
    for (int off = 32; off > 0; off >>= 1)
        wl = fmaxf(wl, __shfl_xor(wl, off, 64));
    float Wmax = wl;
    int base = (b - (is_col ? CBASE : 0)) * RT;

    // wave wv builds rows 2wv, 2wv+1 of A; exact shift M = Wmax*(amax-amin)
    #pragma unroll
    for (int q = 0; q < 2; ++q) {
        int rr = 2 * wv + q;
        int i, j; decomp((unsigned)(base + rr), i, j);
        float s = INV_TEMP * wself[i * NN + j];
        const float* Mi = Mat + i * NN;
        const float* Mj = Mat + j * NN;
        float v0 = s * (Mi[lane] - Mj[lane]);
        A[rr * NN + lane] = v0;
        float vmax = v0, vmin = v0;
        if (lane < 32) {
            float v1 = s * (Mi[64 + lane] - Mj[64 + lane]);
            A[rr * NN + 64 + lane] = v1;
            vmax = fmaxf(vmax, v1); vmin = fminf(vmin, v1);
        }
        #pragma unroll
        for (int off = 32; off > 0; off >>= 1) {
            vmax = fmaxf(vmax, __shfl_xor(vmax, off, 64));
            vmin = fminf(vmin, __shfl_xor(vmin, off, 64));
        }
        if (lane == 0) {
            float M = Wmax * (vmax - vmin);
            Ms[rr] = M;
            M2s[rr] = M * LOG2E;
        }
    }
    __syncthreads();

    int l1 = (lane < 32) ? (64 + lane) : (lane - 32);
    float M2[RT], aL0[RT], aL1[RT], aL2[RT], S[RT];
    #pragma unroll
    for (int r = 0; r < RT; ++r) {
        M2[r] = M2s[r];
        aL0[r] = A[r * NN + lane];
        aL1[r] = A[r * NN + l1];
        aL2[r] = A[r * NN + lane + 32];
        S[r] = 0.f;
    }

    for (int idx = wv; idx < 48; idx += 4) {
        int k0 = 2 * idx, k1 = k0 + 1;
        float w0 = wsweep[k0 * NN + lane];
        float w1 = wsweep[(lane < 32 ? k0 : k1) * NN + l1];
        float w2 = wsweep[k1 * NN + lane + 32];
        #pragma unroll
        for (int r = 0; r < RT; ++r) {
            float2 ak = *(const float2*)&A[r * NN + k0];   // k0 even -> 8B aligned
            float aksel = (lane < 32) ? ak.x : ak.y;
            S[r] += __builtin_amdgcn_exp2f(w0 * (ak.x  - aL0[r]) - M2[r])
                  + __builtin_amdgcn_exp2f(w1 * (aksel - aL1[r]) - M2[r])
                  + __builtin_amdgcn_exp2f(w2 * (ak.y  - aL2[r]) - M2[r]);
        }
    }

    #pragma unroll
    for (int off = 32; off > 0; off >>= 1) {
        #pragma unroll
        for (int r = 0; r < RT; ++r) S[r] += __shfl_xor(S[r], off, 64);
    }
    if (lane == 0) {
        #pragma unroll
        for (int r = 0; r < RT; ++r) wred[wv][r] = S[r];
    }
    __syncthreads();

    if (tid < RT) {
        int r = tid;
        float tot = wred[0][r] + wred[1][r] + wred[2][r] + wred[3][r];
        tot -= 96.f * __builtin_amdgcn_exp2f(-M2s[r]);     // remove w=0 diagonal slots
        cred[r] = Ms[r] + logf(tot) - ws[OFF_DIAG + base + r];
    }
    __syncthreads();
    if (tid == 0) {
        float c = 0.f;
        #pragma unroll
        for (int r = 0; r < RT; ++r) c += cred[r];
        atomicAdd(out, c * (1.0f / (float)NTASK));
    }
}

extern "C" void kernel_launch(void* const* d_in, const int* in_sizes, int n_in,
                              void* d_out, int out_size, void* d_ws, size_t ws_size,
                              hipStream_t stream) {
    const float* txt = (const float*)d_in[0];
    const float* img = (const float*)d_in[1];
    float* ws = (float*)d_ws;
    prep_kernel<<<36, 256, 0, stream>>>(txt, img, ws);
    lse_kernel<<<NBLK_T, 256, 0, stream>>>(ws, (float*)d_out);
}

// Round 4
// 96.383 us; speedup vs baseline: 5.0188x; 1.2520x over previous
//
#include <hip/hip_runtime.h>
#include <math.h>

#define NN 96
#define DD 512
#define PP 9120          // NN*(NN-1)
#define EPSF 1e-8f
#define INV_TEMP 100.0f
#define LOG2E 1.4426950408889634f
#define RT 8             // tasks (rows/cols of mma) per lse block
#define NTASK (2*PP)     // 18240
#define NBLK_T (NTASK/RT) // 2280
#define CBASE (PP/RT)    // 1140: first block index handling column tasks
#define NPBLK 1152       // prep blocks (8 pairs each = 9216)

// ws float-offset layout (no init-dependent state: poison-proof)
#define OFF_G     0        // G  = txt*img^T   [96*96]
#define OFF_GT    9216     // GT = G^T
#define OFF_WT    18432    // wt[k][l] = 1/(||t_k-t_l||+eps), diag 0
#define OFF_WM    27648
#define OFF_WST   36864    // wt * log2e
#define OFF_WSM   46080    // wm * log2e
#define OFF_WMAXS 55296    // [0..1151] per-prep-block max wt, [1152..2303] max wm

__device__ __forceinline__ void decomp(unsigned p, int& i, int& j) {
    unsigned ii = p / 95u;
    unsigned r  = p - ii * 95u;
    i = (int)ii;
    j = (int)(r + (r >= ii ? 1u : 0u));
}

// K1: pair-per-wave prep. 1152 blocks x 4 waves x 2 pairs. Wave loads rows
// t_i,t_j,m_i,m_j coalesced (2 float4/lane), butterfly-reduces <t_i,m_j>,
// ||t_i-t_j||^2, ||m_i-m_j||^2. Writes G/GT/W tables + per-block Wmax partials.
__global__ __launch_bounds__(256) void prep_kernel(const float* __restrict__ txt,
                                                   const float* __restrict__ img,
                                                   float* __restrict__ ws) {
    __shared__ float wtw[4], wmw[4];
    int b = blockIdx.x, tid = threadIdx.x;
    int lane = tid & 63, wv = tid >> 6;
    const float4* T4 = (const float4*)txt;   // row stride 128 float4
    const float4* M4 = (const float4*)img;
    float bwt = 0.f, bwm = 0.f;

    #pragma unroll
    for (int q = 0; q < 2; ++q) {
        int pp = b * 8 + wv * 2 + q;         // 0..9215
        int i = pp / NN, j = pp - i * NN;
        const float4* Ti = T4 + i * 128 + 2 * lane;
        const float4* Tj = T4 + j * 128 + 2 * lane;
        const float4* Mi = M4 + i * 128 + 2 * lane;
        const float4* Mj = M4 + j * 128 + 2 * lane;
        float gij = 0.f, nt2 = 0.f, nm2 = 0.f;
        #pragma unroll
        for (int u = 0; u < 2; ++u) {
            float4 a = Ti[u], t = Tj[u], c = Mi[u], d = Mj[u];
            gij += a.x*d.x + a.y*d.y + a.z*d.z + a.w*d.w;       // <t_i, m_j>
            float d0 = a.x-t.x, d1 = a.y-t.y, d2 = a.z-t.z, d3 = a.w-t.w;
            nt2 += d0*d0 + d1*d1 + d2*d2 + d3*d3;               // ||t_i-t_j||^2
            float e0 = c.x-d.x, e1 = c.y-d.y, e2 = c.z-d.z, e3 = c.w-d.w;
            nm2 += e0*e0 + e1*e1 + e2*e2 + e3*e3;               // ||m_i-m_j||^2
        }
        #pragma unroll
        for (int off = 32; off > 0; off >>= 1) {
            gij += __shfl_xor(gij, off, 64);
            nt2 += __shfl_xor(nt2, off, 64);
            nm2 += __shfl_xor(nm2, off, 64);
        }
        float wt = 0.f, wm = 0.f;
        if (i != j) {
            wt = 1.f / (sqrtf(fmaxf(nt2, 0.f)) + EPSF);
            wm = 1.f / (sqrtf(fmaxf(nm2, 0.f)) + EPSF);
        }
        bwt = fmaxf(bwt, wt); bwm = fmaxf(bwm, wm);
        if (lane == 0) {
            int t0 = i * NN + j;
            ws[OFF_G  + t0] = gij;
            ws[OFF_GT + j * NN + i] = gij;   // mirror pair fills GT[i*NN+j]
            ws[OFF_WT  + t0] = wt;
            ws[OFF_WM  + t0] = wm;
            ws[OFF_WST + t0] = wt * LOG2E;
            ws[OFF_WSM + t0] = wm * LOG2E;
        }
    }
    if (lane == 0) { wtw[wv] = bwt; wmw[wv] = bwm; }
    __syncthreads();
    if (tid == 0) {
        ws[OFF_WMAXS + b]         = fmaxf(fmaxf(wtw[0], wtw[1]), fmaxf(wtw[2], wtw[3]));
        ws[OFF_WMAXS + NPBLK + b] = fmaxf(fmaxf(wmw[0], wmw[1]), fmaxf(wmw[2], wmw[3]));
    }
}

// K2: lse over 2280 blocks (8 tasks each). Wmax from 1152 partials; sweep
// software-pipelined (next-idx w's prefetched in named regs); DIAG computed
// in epilogue from G/W tables. One float atomicAdd into pre-zeroed out.
__global__ __launch_bounds__(256) void lse_kernel(const float* __restrict__ ws,
                                                  float* __restrict__ out) {
    __shared__ float A[RT * NN];
    __shared__ float M2s[RT];     // M * log2e
    __shared__ float Ms[RT];      // M
    __shared__ float wred[4][RT];
    __shared__ float cred[RT];

    int tid = threadIdx.x, lane = tid & 63, wv = tid >> 6;
    int b = blockIdx.x;
    bool is_col = (b >= CBASE);
    const float* Mat    = ws + (is_col ? OFF_GT  : OFF_G);
    const float* wself  = ws + (is_col ? OFF_WM  : OFF_WT);
    const float* wsweep = ws + (is_col ? OFF_WST : OFF_WSM);

    // Wmax: rows sweep wm (partials at NPBLK..), cols sweep wt (partials at 0..)
    const float* wmx = ws + OFF_WMAXS + (is_col ? 0 : NPBLK);
    float wl = 0.f;
    #pragma unroll
    for (int u = 0; u < 18; ++u)             // 18*64 = 1152
        wl = fmaxf(wl, wmx[lane + 64 * u]);
    #pragma unroll
    for (int off = 32; off > 0; off >>= 1)
        wl = fmaxf(wl, __shfl_xor(wl, off, 64));
    float Wmax = wl;
    int base = (b - (is_col ? CBASE : 0)) * RT;

    // wave wv builds rows 2wv, 2wv+1 of A; exact shift M = Wmax*(amax-amin)
    #pragma unroll
    for (int q = 0; q < 2; ++q) {
        int rr = 2 * wv + q;
        int i, j; decomp((unsigned)(base + rr), i, j);
        float s = INV_TEMP * wself[i * NN + j];
        const float* Mi = Mat + i * NN;
        const float* Mj = Mat + j * NN;
        float v0 = s * (Mi[lane] - Mj[lane]);
        A[rr * NN + lane] = v0;
        float vmax = v0, vmin = v0;
        if (lane < 32) {
            float v1 = s * (Mi[64 + lane] - Mj[64 + lane]);
            A[rr * NN + 64 + lane] = v1;
            vmax = fmaxf(vmax, v1); vmin = fminf(vmin, v1);
        }
        #pragma unroll
        for (int off = 32; off > 0; off >>= 1) {
            vmax = fmaxf(vmax, __shfl_xor(vmax, off, 64));
            vmin = fminf(vmin, __shfl_xor(vmin, off, 64));
        }
        if (lane == 0) {
            float M = Wmax * (vmax - vmin);
            Ms[rr] = M;
            M2s[rr] = M * LOG2E;
        }
    }
    __syncthreads();

    int l1 = (lane < 32) ? (64 + lane) : (lane - 32);
    float M2[RT], aL0[RT], aL1[RT], aL2[RT], S[RT];
    #pragma unroll
    for (int r = 0; r < RT; ++r) {
        M2[r] = M2s[r];
        aL0[r] = A[r * NN + lane];
        aL1[r] = A[r * NN + l1];
        aL2[r] = A[r * NN + lane + 32];
        S[r] = 0.f;
    }

    // wave wv handles idx in {wv, wv+4, ...}, 12 iterations; w's prefetched
    // one iteration ahead in named registers (no runtime-indexed arrays).
    {
        int k0n = 2 * wv;
        float nw0 = wsweep[k0n * NN + lane];
        float nw1 = wsweep[(lane < 32 ? k0n : k0n + 1) * NN + l1];
        float nw2 = wsweep[(k0n + 1) * NN + lane + 32];
        for (int u = 0; u < 12; ++u) {
            int k0 = 2 * (wv + 4 * u);
            float w0 = nw0, w1 = nw1, w2 = nw2;
            if (u < 11) {
                int nk0 = 2 * (wv + 4 * (u + 1));
                nw0 = wsweep[nk0 * NN + lane];
                nw1 = wsweep[(lane < 32 ? nk0 : nk0 + 1) * NN + l1];
                nw2 = wsweep[(nk0 + 1) * NN + lane + 32];
            }
            #pragma unroll
            for (int r = 0; r < RT; ++r) {
                float2 ak = *(const float2*)&A[r * NN + k0];   // k0 even -> 8B aligned
                float aksel = (lane < 32) ? ak.x : ak.y;
                S[r] += __builtin_amdgcn_exp2f(w0 * (ak.x  - aL0[r]) - M2[r])
                      + __builtin_amdgcn_exp2f(w1 * (aksel - aL1[r]) - M2[r])
                      + __builtin_amdgcn_exp2f(w2 * (ak.y  - aL2[r]) - M2[r]);
            }
        }
    }

    #pragma unroll
    for (int off = 32; off > 0; off >>= 1) {
        #pragma unroll
        for (int r = 0; r < RT; ++r) S[r] += __shfl_xor(S[r], off, 64);
    }
    if (lane == 0) {
        #pragma unroll
        for (int r = 0; r < RT; ++r) wred[wv][r] = S[r];
    }
    __syncthreads();

    if (tid < RT) {
        int r = tid;
        float tot = wred[0][r] + wred[1][r] + wred[2][r] + wred[3][r];
        tot -= 96.f * __builtin_amdgcn_exp2f(-M2s[r]);     // remove w=0 diagonal slots
        int i, j; decomp((unsigned)(base + r), i, j);
        float wtv = ws[OFF_WT + i * NN + j];
        float wmv = ws[OFF_WM + i * NN + j];
        float gii = ws[OFF_G + i * NN + i], gjj = ws[OFF_G + j * NN + j];
        float gij = ws[OFF_G + i * NN + j], gji = ws[OFF_G + j * NN + i];
        float dia = INV_TEMP * wtv * wmv * (gii - gij - gji + gjj);
        cred[r] = Ms[r] + logf(tot) - dia;
    }
    __syncthreads();
    if (tid == 0) {
        float c = 0.f;
        #pragma unroll
        for (int r = 0; r < RT; ++r) c += cred[r];
        atomicAdd(out, c * (1.0f / (float)NTASK));   // out pre-zeroed by harness
    }
}

extern "C" void kernel_launch(void* const* d_in, const int* in_sizes, int n_in,
                              void* d_out, int out_size, void* d_ws, size_t ws_size,
                              hipStream_t stream) {
    const float* txt = (const float*)d_in[0];
    const float* img = (const float*)d_in[1];
    float* ws = (float*)d_ws;
    prep_kernel<<<NPBLK, 256, 0, stream>>>(txt, img, ws);
    lse_kernel<<<NBLK_T, 256, 0, stream>>>(ws, (float*)d_out);
}